// Round 4
// baseline (484.074 us; speedup 1.0000x reference)
//
#include <hip/hip_runtime.h>
#include <hip/hip_cooperative_groups.h>

namespace cg = cooperative_groups;

#define HW 129600
#define WG 360
#define HG 360
#define NCLS 10
#define NPROP 200
#define CDIM 128
#define NROWS 80000
#define NB 2
#define SEL_CAP 2048
#define HBINS 4096        // heat in (0,1]: (bits>>18) <= 0x3F80>>2 = 4064
#define RPB 64            // rows per k_head block
#define TOTAL (NB * NCLS * HW)   // 2,592,000
#define BH (NCLS * HW)           // 1,296,000
#define SBLK 1024         // k_select grid (cooperative)
#define SPT 10            // positions/thread: 1024*256*10 >= TOTAL

// ---------------------------------------------------------------------------
// Shared NMS value: 3x3 local-max suppression, classes 8/9 pass-through,
// border rows/cols suppressed (reference's local_max stays 0 there).
// ---------------------------------------------------------------------------
__device__ __forceinline__ float nms_val(const float* __restrict__ hp, int pos,
                                         int cl) {
  float v = hp[pos];
  if (cl >= 8) return v;
  int y = pos / WG, x = pos - y * WG;
  if (y == 0 || y == HG - 1 || x == 0 || x == WG - 1) return 0.f;
  float m = v;
  m = fmaxf(m, hp[pos - 1]);
  m = fmaxf(m, hp[pos + 1]);
  m = fmaxf(m, hp[pos - WG - 1]);
  m = fmaxf(m, hp[pos - WG]);
  m = fmaxf(m, hp[pos - WG + 1]);
  m = fmaxf(m, hp[pos + WG - 1]);
  m = fmaxf(m, hp[pos + WG]);
  m = fmaxf(m, hp[pos + WG + 1]);
  return (v == m) ? v : 0.f;
}

// ---------------------------------------------------------------------------
// K1: fused MLP head. 256 thr / 64 rows; R2-style LDS tiling (acc[8][4]) +
// register-prefetch pipeline. Layer-1 k ascending (as R2/R3, both passed).
// Layer-2: h staged to LDS in two 32-row halves, R2's rotated-dot scheme.
// ---------------------------------------------------------------------------
__global__ __launch_bounds__(256) void k_head(
    const float* __restrict__ feat, const float* __restrict__ W1,
    const float* __restrict__ b1, const float* __restrict__ W2,
    const float* __restrict__ b2, const int* __restrict__ idxs,
    float* __restrict__ dense_heat, int* __restrict__ rowmap) {
  __shared__ __align__(16) float lds_w[32 * 128];     // 16KB: W1 chunk; reused as h
  __shared__ __align__(16) float lds_f[RPB * 32];     // 8KB: f chunk
  __shared__ __align__(16) float lds_w2t[NCLS * 128]; // 5KB: W2^T
  __shared__ int lds_b[RPB];
  __shared__ int lds_p[RPB];
  const int tid = threadIdx.x;
  const int row0 = blockIdx.x * RPB;
  const int tc = tid & 31;
  const int tr = tid >> 5;

  for (int i = tid; i < CDIM * NCLS; i += 256) {
    int k = i / NCLS, j = i - k * NCLS;
    lds_w2t[j * 128 + k] = W2[i];
  }
  if (tid < RPB) {
    int row = row0 + tid;
    int bb = idxs[row * 3 + 0];
    int yy = idxs[row * 3 + 1];
    int xx = idxs[row * 3 + 2];
    lds_b[tid] = bb;
    lds_p[tid] = yy * WG + xx;
    rowmap[(size_t)bb * HW + yy * WG + xx] = row;
  }
#pragma unroll
  for (int q = 0; q < 4; ++q) {
    int fi = tid + q * 256;
    *(float4*)(lds_w + fi * 4) = *(const float4*)(W1 + fi * 4);
  }
#pragma unroll
  for (int q = 0; q < 2; ++q) {
    int fi = tid + q * 256;
    int r = fi >> 3, kk = fi & 7;
    *(float4*)(lds_f + r * 32 + kk * 4) =
        *(const float4*)(feat + (size_t)(row0 + r) * CDIM + kk * 4);
  }
  __syncthreads();

  float acc[8][4];
#pragma unroll
  for (int r = 0; r < 8; ++r)
#pragma unroll
    for (int c = 0; c < 4; ++c) acc[r][c] = 0.f;

  for (int kt = 0; kt < 4; ++kt) {
    float4 pw[4], pf[2];
    if (kt < 3) {  // issue next-chunk loads; latency overlaps compute below
#pragma unroll
      for (int q = 0; q < 4; ++q)
        pw[q] = *(const float4*)(W1 + (kt + 1) * 4096 + (tid + q * 256) * 4);
#pragma unroll
      for (int q = 0; q < 2; ++q) {
        int fi = tid + q * 256;
        int r = fi >> 3, kk = fi & 7;
        pf[q] = *(const float4*)(feat + (size_t)(row0 + r) * CDIM +
                                 (kt + 1) * 32 + kk * 4);
      }
    }
#pragma unroll
    for (int kg = 0; kg < 8; ++kg) {
      float4 w0 = *(const float4*)(lds_w + (kg * 4 + 0) * 128 + tc * 4);
      float4 w1 = *(const float4*)(lds_w + (kg * 4 + 1) * 128 + tc * 4);
      float4 w2 = *(const float4*)(lds_w + (kg * 4 + 2) * 128 + tc * 4);
      float4 w3 = *(const float4*)(lds_w + (kg * 4 + 3) * 128 + tc * 4);
#pragma unroll
      for (int r = 0; r < 8; ++r) {
        float4 fv = *(const float4*)(lds_f + (tr * 8 + r) * 32 + kg * 4);
        acc[r][0] = fmaf(fv.x, w0.x, acc[r][0]);
        acc[r][0] = fmaf(fv.y, w1.x, acc[r][0]);
        acc[r][0] = fmaf(fv.z, w2.x, acc[r][0]);
        acc[r][0] = fmaf(fv.w, w3.x, acc[r][0]);
        acc[r][1] = fmaf(fv.x, w0.y, acc[r][1]);
        acc[r][1] = fmaf(fv.y, w1.y, acc[r][1]);
        acc[r][1] = fmaf(fv.z, w2.y, acc[r][1]);
        acc[r][1] = fmaf(fv.w, w3.y, acc[r][1]);
        acc[r][2] = fmaf(fv.x, w0.z, acc[r][2]);
        acc[r][2] = fmaf(fv.y, w1.z, acc[r][2]);
        acc[r][2] = fmaf(fv.z, w2.z, acc[r][2]);
        acc[r][2] = fmaf(fv.w, w3.z, acc[r][2]);
        acc[r][3] = fmaf(fv.x, w0.w, acc[r][3]);
        acc[r][3] = fmaf(fv.y, w1.w, acc[r][3]);
        acc[r][3] = fmaf(fv.z, w2.w, acc[r][3]);
        acc[r][3] = fmaf(fv.w, w3.w, acc[r][3]);
      }
    }
    __syncthreads();
    if (kt < 3) {
#pragma unroll
      for (int q = 0; q < 4; ++q) *(float4*)(lds_w + (tid + q * 256) * 4) = pw[q];
#pragma unroll
      for (int q = 0; q < 2; ++q) {
        int fi = tid + q * 256;
        int r = fi >> 3, kk = fi & 7;
        *(float4*)(lds_f + r * 32 + kk * 4) = pf[q];
      }
    }
    __syncthreads();
  }

  float4 b1v = *(const float4*)(b1 + tc * 4);
#pragma unroll
  for (int half = 0; half < 2; ++half) {
    if ((tr >> 2) == half) {  // wave-uniform: waves 0,1 = half0; 2,3 = half1
      int ltr = tr & 3;
#pragma unroll
      for (int r = 0; r < 8; ++r) {
        float4 h;
        h.x = fmaxf(acc[r][0] + b1v.x, 0.f);
        h.y = fmaxf(acc[r][1] + b1v.y, 0.f);
        h.z = fmaxf(acc[r][2] + b1v.z, 0.f);
        h.w = fmaxf(acc[r][3] + b1v.w, 0.f);
        *(float4*)(lds_w + (ltr * 8 + r) * 128 + tc * 4) = h;
      }
    }
    __syncthreads();
    for (int o = tid; o < 32 * NCLS; o += 256) {
      int r = o / NCLS, j = o - r * NCLS;
      float s = b2[j];
      for (int i4 = 0; i4 < 32; ++i4) {
        int k4 = (i4 + tid) & 31;
        float4 hv = *(const float4*)(lds_w + r * 128 + k4 * 4);
        float4 wv = *(const float4*)(lds_w2t + j * 128 + k4 * 4);
        s = fmaf(hv.x, wv.x, s);
        s = fmaf(hv.y, wv.y, s);
        s = fmaf(hv.z, wv.z, s);
        s = fmaf(hv.w, wv.w, s);
      }
      float heat = 1.0f / (1.0f + expf(-s));
      int gr = half * 32 + r;
      dense_heat[((size_t)lds_b[gr] * NCLS + j) * HW + lds_p[gr]] = heat;
    }
    __syncthreads();
  }
}

// ---------------------------------------------------------------------------
// K2 (cooperative): single scan of dense_heat.
// Phase 1: NMS vals -> regs + LDS hist (per-batch exact: straddling block
// sends minority-batch counts straight to global). grid.sync.
// Phase 2: thresholds from hist; compact survivors from regs. grid.sync.
// Phase 3: blocks 0/1 rank-count the top-200 and emit all outputs.
// ---------------------------------------------------------------------------
__global__ __launch_bounds__(256) void k_select(
    const float* __restrict__ dense_heat, unsigned int* __restrict__ hist,
    unsigned long long* __restrict__ sel, int* __restrict__ sel_cnt,
    const int* __restrict__ rowmap, const float* __restrict__ feat,
    const float* __restrict__ Wc, const float* __restrict__ bc,
    float* __restrict__ out) {
  __shared__ __align__(16) unsigned long long sk[SEL_CAP];  // 16KB
  __shared__ int sT[2];
  __shared__ unsigned long long winners[NPROP];
  __shared__ int wpos[NPROP];
  __shared__ int wcls[NPROP];
  __shared__ int wrow[NPROP];
  unsigned int* lh = (unsigned int*)sk;  // alias: 4096-bin hist, then coarse
  cg::grid_group grid = cg::this_grid();
  const int tid = threadIdx.x;
  const int gbase = blockIdx.x * (256 * SPT);
  const int blk_b = (gbase < BH) ? 0 : 1;  // LDS hist belongs to this batch

  for (int i = tid; i < HBINS; i += 256) lh[i] = 0;
  __syncthreads();
  float val[SPT];
#pragma unroll
  for (int it = 0; it < SPT; ++it) {
    int g = gbase + it * 256 + tid;
    float v = 0.f;
    if (g < TOTAL) {
      int b = (g >= BH) ? 1 : 0;
      int r = g - b * BH;
      int cl = r / HW;
      int pos = r - cl * HW;
      v = nms_val(dense_heat + (size_t)(g - pos), pos, cl);
      if (v > 0.f) {
        unsigned int bin = __float_as_uint(v) >> 18;
        if (b == blk_b)
          atomicAdd(&lh[bin], 1u);
        else  // rare: straddling block's minority batch -> direct global
          atomicAdd(&hist[(size_t)b * HBINS + bin], 1u);
      }
    }
    val[it] = v;
  }
  __syncthreads();
  {
    unsigned int* gh = hist + (size_t)blk_b * HBINS;
    for (int i = tid; i < HBINS; i += 256) {
      unsigned int c = lh[i];
      if (c) atomicAdd(&gh[i], c);
    }
  }
  grid.sync();

  for (int bb = 0; bb < NB; ++bb) {
    const unsigned int* h = hist + (size_t)bb * HBINS;
    unsigned int s = 0;
#pragma unroll
    for (int i = 0; i < HBINS / 256; ++i) s += h[tid * (HBINS / 256) + i];
    __syncthreads();  // lh free for reuse as coarse
    lh[tid] = s;
    __syncthreads();
    if (tid == 0) {
      unsigned int cum = 0;
      int T = 0;
      int ci = 255;
      for (; ci >= 0; --ci) {
        if (cum + lh[ci] >= NPROP) break;
        cum += lh[ci];
      }
      if (ci >= 0) {
        int t = 15;
        for (; t > 0; --t) {
          unsigned int c = h[ci * 16 + t];
          if (cum + c >= NPROP) break;
          cum += c;
        }
        T = ci * 16 + t;
      }
      sT[bb] = T;
    }
    __syncthreads();
  }
  const int T0 = sT[0], T1 = sT[1];
#pragma unroll
  for (int it = 0; it < SPT; ++it) {
    int g = gbase + it * 256 + tid;
    float v = (g < TOTAL) ? val[it] : 0.f;
    int b = (g >= BH) ? 1 : 0;
    unsigned int bits = __float_as_uint(v);
    bool pred = (v > 0.f) && ((int)(bits >> 18) >= (b ? T1 : T0));
    unsigned long long mask = __ballot(pred);
    if (pred) {
      int lane = tid & 63;
      int lb = __popcll(mask & ((1ull << lane) - 1ull));
      int base = 0;
      if (lb == 0) base = atomicAdd(&sel_cnt[b], (int)__popcll(mask));
      base = __builtin_amdgcn_readfirstlane(base);
      unsigned int gidx = (unsigned int)(g - b * BH);
      // key: heat bits desc, then smaller gidx first (jax top_k tie-break)
      unsigned long long key =
          ((unsigned long long)bits << 32) | (unsigned long long)(~gidx);
      int slot = base + lb;
      if (slot < SEL_CAP) sel[(size_t)b * SEL_CAP + slot] = key;
    }
  }
  grid.sync();

  const int b = blockIdx.x;
  if (b >= NB) return;
  int M = sel_cnt[b];
  if (M > SEL_CAP) M = SEL_CAP;
  for (int i = tid; i < M; i += 256) sk[i] = sel[(size_t)b * SEL_CAP + i];
  __syncthreads();
  for (int i = tid; i < M; i += 256) {
    unsigned long long key = sk[i];
    int rank = 0;
    for (int j = 0; j < M; ++j) rank += (sk[j] > key) ? 1 : 0;
    if (rank < NPROP) winners[rank] = key;
  }
  __syncthreads();
  if (tid < NPROP) {
    unsigned long long key = winners[tid];
    unsigned int gidx = ~((unsigned int)(key & 0xFFFFFFFFull));
    int cls = (int)(gidx / HW);
    int pos = (int)(gidx - (unsigned int)cls * HW);
    int y = pos / WG, x = pos - y * WG;
    wpos[tid] = pos;
    wcls[tid] = cls;
    wrow[tid] = rowmap[(size_t)b * HW + pos];
    out[51200 + ((size_t)b * NPROP + tid) * 2 + 0] = (float)x;
    out[51200 + ((size_t)b * NPROP + tid) * 2 + 1] = (float)y;
    out[56000 + b * NPROP + tid] = (float)cls;
  }
  __syncthreads();
  for (int o = tid; o < NCLS * NPROP; o += 256) {
    int j = o / NPROP, pp = o - j * NPROP;
    const float* hp = dense_heat + ((size_t)b * NCLS + j) * HW;
    out[52000 + (size_t)b * NCLS * NPROP + o] = nms_val(hp, wpos[pp], j);
  }
  for (int o = tid; o < CDIM * NPROP; o += 256) {
    int c = o / NPROP, pp = o - c * NPROP;
    out[(size_t)b * CDIM * NPROP + o] =
        feat[(size_t)wrow[pp] * CDIM + c] + Wc[c * NCLS + wcls[pp]] + bc[c];
  }
}

// ---------------------------------------------------------------------------
// ws layout (bytes):
//   [0)          dense_heat : B*10*HW*4 = 10,368,000
//   [10368000)   hist       : B*4096*4  =     32,768
//   [10400768)   rowmap     : B*HW*4    =  1,036,800
//   [11437568)   sel        : B*2048*8  =     32,768
//   [11470336)   cnts       : sel_cnt[2]
// ---------------------------------------------------------------------------
extern "C" void kernel_launch(void* const* d_in, const int* in_sizes, int n_in,
                              void* d_out, int out_size, void* d_ws,
                              size_t ws_size, hipStream_t stream) {
  const float* feat = (const float*)d_in[0];
  const float* W1 = (const float*)d_in[1];
  const float* b1 = (const float*)d_in[2];
  const float* W2 = (const float*)d_in[3];
  const float* b2 = (const float*)d_in[4];
  const float* Wc = (const float*)d_in[5];
  const float* bc = (const float*)d_in[6];
  const int* idxs = (const int*)d_in[7];
  float* out = (float*)d_out;

  char* ws = (char*)d_ws;
  float* dense_heat = (float*)(ws + 0);
  unsigned int* hist = (unsigned int*)(ws + 10368000);
  int* rowmap = (int*)(ws + 10400768);
  unsigned long long* sel = (unsigned long long*)(ws + 11437568);
  int* sel_cnt = (int*)(ws + 11470336);

  hipMemsetAsync(dense_heat, 0, (size_t)NB * NCLS * HW * sizeof(float), stream);
  hipMemsetAsync(hist, 0, (size_t)NB * HBINS * sizeof(unsigned int), stream);
  hipMemsetAsync(sel_cnt, 0, 2 * sizeof(int), stream);

  k_head<<<NROWS / RPB, 256, 0, stream>>>(feat, W1, b1, W2, b2, idxs, dense_heat,
                                          rowmap);
  void* args[] = {(void*)&dense_heat, (void*)&hist,   (void*)&sel,
                  (void*)&sel_cnt,    (void*)&rowmap, (void*)&feat,
                  (void*)&Wc,         (void*)&bc,     (void*)&out};
  hipLaunchCooperativeKernel((const void*)k_select, dim3(SBLK), dim3(256), args,
                             0, stream);
}

// Round 5
// 315.255 us; speedup vs baseline: 1.5355x; 1.5355x over previous
//
#include <hip/hip_runtime.h>

#define HW 129600
#define WG 360
#define HG 360
#define NCLS 10
#define NPROP 200
#define CDIM 128
#define NROWS 80000
#define NB 2
#define SEL_CAP 4096
#define HBINS 4096        // heat in (0,1]: (bits>>18) <= 0x3F80>>2 = 4064
#define RPB 64            // rows per k_head block
#define NRC (NROWS * NCLS)  // 800,000 sparse NMS sites

// ---------------------------------------------------------------------------
// Shared NMS value: 3x3 local-max suppression, classes 8/9 pass-through,
// border rows/cols suppressed (reference's local_max stays 0 there).
// ---------------------------------------------------------------------------
__device__ __forceinline__ float nms_val(const float* __restrict__ hp, int pos,
                                         int cl) {
  float v = hp[pos];
  if (cl >= 8) return v;
  int y = pos / WG, x = pos - y * WG;
  if (y == 0 || y == HG - 1 || x == 0 || x == WG - 1) return 0.f;
  float m = v;
  m = fmaxf(m, hp[pos - 1]);
  m = fmaxf(m, hp[pos + 1]);
  m = fmaxf(m, hp[pos - WG - 1]);
  m = fmaxf(m, hp[pos - WG]);
  m = fmaxf(m, hp[pos - WG + 1]);
  m = fmaxf(m, hp[pos + WG - 1]);
  m = fmaxf(m, hp[pos + WG]);
  m = fmaxf(m, hp[pos + WG + 1]);
  return (v == m) ? v : 0.f;
}

// ---------------------------------------------------------------------------
// K1: fused MLP head (R4's verified version). 256 thr / 64 rows; LDS tiling
// (acc[8][4]) + register-prefetch pipeline. 29.8 KB LDS -> 5 blocks/CU.
// ---------------------------------------------------------------------------
__global__ __launch_bounds__(256) void k_head(
    const float* __restrict__ feat, const float* __restrict__ W1,
    const float* __restrict__ b1, const float* __restrict__ W2,
    const float* __restrict__ b2, const int* __restrict__ idxs,
    float* __restrict__ dense_heat, int* __restrict__ rowmap) {
  __shared__ __align__(16) float lds_w[32 * 128];     // 16KB: W1 chunk; reused as h
  __shared__ __align__(16) float lds_f[RPB * 32];     // 8KB: f chunk
  __shared__ __align__(16) float lds_w2t[NCLS * 128]; // 5KB: W2^T
  __shared__ int lds_b[RPB];
  __shared__ int lds_p[RPB];
  const int tid = threadIdx.x;
  const int row0 = blockIdx.x * RPB;
  const int tc = tid & 31;
  const int tr = tid >> 5;

  for (int i = tid; i < CDIM * NCLS; i += 256) {
    int k = i / NCLS, j = i - k * NCLS;
    lds_w2t[j * 128 + k] = W2[i];
  }
  if (tid < RPB) {
    int row = row0 + tid;
    int bb = idxs[row * 3 + 0];
    int yy = idxs[row * 3 + 1];
    int xx = idxs[row * 3 + 2];
    lds_b[tid] = bb;
    lds_p[tid] = yy * WG + xx;
    rowmap[(size_t)bb * HW + yy * WG + xx] = row;
  }
#pragma unroll
  for (int q = 0; q < 4; ++q) {
    int fi = tid + q * 256;
    *(float4*)(lds_w + fi * 4) = *(const float4*)(W1 + fi * 4);
  }
#pragma unroll
  for (int q = 0; q < 2; ++q) {
    int fi = tid + q * 256;
    int r = fi >> 3, kk = fi & 7;
    *(float4*)(lds_f + r * 32 + kk * 4) =
        *(const float4*)(feat + (size_t)(row0 + r) * CDIM + kk * 4);
  }
  __syncthreads();

  float acc[8][4];
#pragma unroll
  for (int r = 0; r < 8; ++r)
#pragma unroll
    for (int c = 0; c < 4; ++c) acc[r][c] = 0.f;

  for (int kt = 0; kt < 4; ++kt) {
    float4 pw[4], pf[2];
    if (kt < 3) {  // issue next-chunk loads; latency overlaps compute below
#pragma unroll
      for (int q = 0; q < 4; ++q)
        pw[q] = *(const float4*)(W1 + (kt + 1) * 4096 + (tid + q * 256) * 4);
#pragma unroll
      for (int q = 0; q < 2; ++q) {
        int fi = tid + q * 256;
        int r = fi >> 3, kk = fi & 7;
        pf[q] = *(const float4*)(feat + (size_t)(row0 + r) * CDIM +
                                 (kt + 1) * 32 + kk * 4);
      }
    }
#pragma unroll
    for (int kg = 0; kg < 8; ++kg) {
      float4 w0 = *(const float4*)(lds_w + (kg * 4 + 0) * 128 + tc * 4);
      float4 w1 = *(const float4*)(lds_w + (kg * 4 + 1) * 128 + tc * 4);
      float4 w2 = *(const float4*)(lds_w + (kg * 4 + 2) * 128 + tc * 4);
      float4 w3 = *(const float4*)(lds_w + (kg * 4 + 3) * 128 + tc * 4);
#pragma unroll
      for (int r = 0; r < 8; ++r) {
        float4 fv = *(const float4*)(lds_f + (tr * 8 + r) * 32 + kg * 4);
        acc[r][0] = fmaf(fv.x, w0.x, acc[r][0]);
        acc[r][0] = fmaf(fv.y, w1.x, acc[r][0]);
        acc[r][0] = fmaf(fv.z, w2.x, acc[r][0]);
        acc[r][0] = fmaf(fv.w, w3.x, acc[r][0]);
        acc[r][1] = fmaf(fv.x, w0.y, acc[r][1]);
        acc[r][1] = fmaf(fv.y, w1.y, acc[r][1]);
        acc[r][1] = fmaf(fv.z, w2.y, acc[r][1]);
        acc[r][1] = fmaf(fv.w, w3.y, acc[r][1]);
        acc[r][2] = fmaf(fv.x, w0.z, acc[r][2]);
        acc[r][2] = fmaf(fv.y, w1.z, acc[r][2]);
        acc[r][2] = fmaf(fv.z, w2.z, acc[r][2]);
        acc[r][2] = fmaf(fv.w, w3.z, acc[r][2]);
        acc[r][3] = fmaf(fv.x, w0.w, acc[r][3]);
        acc[r][3] = fmaf(fv.y, w1.w, acc[r][3]);
        acc[r][3] = fmaf(fv.z, w2.w, acc[r][3]);
        acc[r][3] = fmaf(fv.w, w3.w, acc[r][3]);
      }
    }
    __syncthreads();
    if (kt < 3) {
#pragma unroll
      for (int q = 0; q < 4; ++q) *(float4*)(lds_w + (tid + q * 256) * 4) = pw[q];
#pragma unroll
      for (int q = 0; q < 2; ++q) {
        int fi = tid + q * 256;
        int r = fi >> 3, kk = fi & 7;
        *(float4*)(lds_f + r * 32 + kk * 4) = pf[q];
      }
    }
    __syncthreads();
  }

  float4 b1v = *(const float4*)(b1 + tc * 4);
#pragma unroll
  for (int half = 0; half < 2; ++half) {
    if ((tr >> 2) == half) {  // wave-uniform: waves 0,1 = half0; 2,3 = half1
      int ltr = tr & 3;
#pragma unroll
      for (int r = 0; r < 8; ++r) {
        float4 h;
        h.x = fmaxf(acc[r][0] + b1v.x, 0.f);
        h.y = fmaxf(acc[r][1] + b1v.y, 0.f);
        h.z = fmaxf(acc[r][2] + b1v.z, 0.f);
        h.w = fmaxf(acc[r][3] + b1v.w, 0.f);
        *(float4*)(lds_w + (ltr * 8 + r) * 128 + tc * 4) = h;
      }
    }
    __syncthreads();
    for (int o = tid; o < 32 * NCLS; o += 256) {
      int r = o / NCLS, j = o - r * NCLS;
      float s = b2[j];
      for (int i4 = 0; i4 < 32; ++i4) {
        int k4 = (i4 + tid) & 31;
        float4 hv = *(const float4*)(lds_w + r * 128 + k4 * 4);
        float4 wv = *(const float4*)(lds_w2t + j * 128 + k4 * 4);
        s = fmaf(hv.x, wv.x, s);
        s = fmaf(hv.y, wv.y, s);
        s = fmaf(hv.z, wv.z, s);
        s = fmaf(hv.w, wv.w, s);
      }
      float heat = 1.0f / (1.0f + expf(-s));
      int gr = half * 32 + r;
      dense_heat[((size_t)lds_b[gr] * NCLS + j) * HW + lds_p[gr]] = heat;
    }
    __syncthreads();
  }
}

// ---------------------------------------------------------------------------
// K2: SPARSE NMS + histogram. Only occupied pixels (from idxs) can be
// positive: 800k sites instead of 2.59M dense positions. Stores every NMS
// value to a compact val[] array for the collect pass. Per-block LDS hist
// (16 KB); a block's minority-batch sites (straddle only) go direct-global.
// ---------------------------------------------------------------------------
__global__ __launch_bounds__(256) void k_hist(
    const float* __restrict__ dense_heat, const int* __restrict__ idxs,
    float* __restrict__ val, unsigned int* __restrict__ hist) {
  __shared__ unsigned int lh[HBINS];
  const int tid = threadIdx.x;
  const int t = blockIdx.x * 256 + tid;  // grid exact: t < NRC
  for (int i = tid; i < HBINS; i += 256) lh[i] = 0;
  __syncthreads();
  const int row = t / NCLS;
  const int cl = t - row * NCLS;
  const int bb = idxs[row * 3 + 0];
  const int pos = idxs[row * 3 + 1] * WG + idxs[row * 3 + 2];
  float v = nms_val(dense_heat + ((size_t)bb * NCLS + cl) * HW, pos, cl);
  val[t] = v;
  // perf hint only; correctness holds regardless via the bb==blk_b test
  const int blk_b = ((blockIdx.x * 256) / NCLS < NROWS / NB) ? 0 : 1;
  if (v > 0.f) {
    unsigned int bin = __float_as_uint(v) >> 18;
    if (bb == blk_b)
      atomicAdd(&lh[bin], 1u);
    else
      atomicAdd(&hist[(size_t)bb * HBINS + bin], 1u);
  }
  __syncthreads();
  unsigned int* gh = hist + (size_t)blk_b * HBINS;
  for (int i = tid; i < HBINS; i += 256) {
    unsigned int c = lh[i];
    if (c) atomicAdd(&gh[i], c);
  }
}

// ---------------------------------------------------------------------------
// K3: threshold bin T per batch: count(bin > T) < 200 <= count(bin >= T).
// ---------------------------------------------------------------------------
__global__ __launch_bounds__(256) void k_thresh(
    const unsigned int* __restrict__ hist, int* __restrict__ selT) {
  __shared__ unsigned int coarse[256];
  const int b = blockIdx.x;
  const unsigned int* h = hist + (size_t)b * HBINS;
  unsigned int s = 0;
#pragma unroll
  for (int i = 0; i < HBINS / 256; ++i) s += h[threadIdx.x * (HBINS / 256) + i];
  coarse[threadIdx.x] = s;
  __syncthreads();
  if (threadIdx.x == 0) {
    unsigned int cum = 0;
    int T = 0;
    int ci = 255;
    for (; ci >= 0; --ci) {
      if (cum + coarse[ci] >= NPROP) break;
      cum += coarse[ci];
    }
    if (ci >= 0) {
      int t = 15;
      for (; t > 0; --t) {
        unsigned int c = h[ci * 16 + t];
        if (cum + c >= NPROP) break;
        cum += c;
      }
      T = ci * 16 + t;
    }
    selT[b] = T;
  }
}

// ---------------------------------------------------------------------------
// K4: compact survivors from the stored vals (coalesced read, no re-stencil).
// Per-batch ballots + shfl-from-leader handle the batch-straddling wave.
// ---------------------------------------------------------------------------
__global__ __launch_bounds__(256) void k_collect(
    const float* __restrict__ val, const int* __restrict__ idxs,
    const int* __restrict__ selT, unsigned long long* __restrict__ sel,
    int* __restrict__ sel_cnt) {
  const int t = blockIdx.x * 256 + threadIdx.x;  // exact grid
  const int row = t / NCLS;
  const int cl = t - row * NCLS;
  float v = val[t];
  unsigned int bits = __float_as_uint(v);
  int bb = 0;
  bool pred = (v > 0.f);
  if (pred) {
    bb = idxs[row * 3 + 0];
    pred = ((int)(bits >> 18) >= selT[bb]);
  }
  unsigned long long m0 = __ballot(pred && (bb == 0));
  unsigned long long m1 = __ballot(pred && (bb == 1));
  if (pred) {
    unsigned long long mask = bb ? m1 : m0;
    int lane = threadIdx.x & 63;
    int leader = __ffsll((unsigned long long)mask) - 1;
    int lb = __popcll(mask & ((1ull << lane) - 1ull));
    int base = 0;
    if (lane == leader) base = atomicAdd(&sel_cnt[bb], (int)__popcll(mask));
    base = __shfl(base, leader, 64);
    unsigned int pos = (unsigned int)(idxs[row * 3 + 1] * WG + idxs[row * 3 + 2]);
    unsigned int gidx = (unsigned int)cl * HW + pos;
    // key: heat bits desc, then smaller gidx first (jax top_k tie-break)
    unsigned long long key =
        ((unsigned long long)bits << 32) | (unsigned long long)(~gidx);
    int slot = base + lb;
    if (slot < SEL_CAP) sel[(size_t)bb * SEL_CAP + slot] = key;
  }
}

// ---------------------------------------------------------------------------
// K5: exact top-200 by rank-counting (keys unique), cooperative emit.
// ---------------------------------------------------------------------------
__global__ __launch_bounds__(256) void k_final(
    const unsigned long long* __restrict__ sel, const int* __restrict__ sel_cnt,
    const float* __restrict__ dense_heat, const int* __restrict__ rowmap,
    const float* __restrict__ feat, const float* __restrict__ Wc,
    const float* __restrict__ bc, float* __restrict__ out) {
  __shared__ unsigned long long sk[SEL_CAP];
  __shared__ unsigned long long winners[NPROP];
  __shared__ int wpos[NPROP];
  __shared__ int wcls[NPROP];
  __shared__ int wrow[NPROP];
  const int b = blockIdx.x;
  const int tid = threadIdx.x;
  int M = sel_cnt[b];
  if (M > SEL_CAP) M = SEL_CAP;
  for (int i = tid; i < M; i += 256) sk[i] = sel[(size_t)b * SEL_CAP + i];
  __syncthreads();
  for (int i = tid; i < M; i += 256) {
    unsigned long long key = sk[i];
    int rank = 0;
    for (int j = 0; j < M; ++j) rank += (sk[j] > key) ? 1 : 0;
    if (rank < NPROP) winners[rank] = key;
  }
  __syncthreads();
  if (tid < NPROP) {
    unsigned long long key = winners[tid];
    unsigned int gidx = ~((unsigned int)(key & 0xFFFFFFFFull));
    int cls = (int)(gidx / HW);
    int pos = (int)(gidx - (unsigned int)cls * HW);
    int y = pos / WG, x = pos - y * WG;
    wpos[tid] = pos;
    wcls[tid] = cls;
    wrow[tid] = rowmap[(size_t)b * HW + pos];
    out[51200 + ((size_t)b * NPROP + tid) * 2 + 0] = (float)x;
    out[51200 + ((size_t)b * NPROP + tid) * 2 + 1] = (float)y;
    out[56000 + b * NPROP + tid] = (float)cls;
  }
  __syncthreads();
  for (int o = tid; o < NCLS * NPROP; o += 256) {
    int j = o / NPROP, pp = o - j * NPROP;
    const float* hp = dense_heat + ((size_t)b * NCLS + j) * HW;
    out[52000 + (size_t)b * NCLS * NPROP + o] = nms_val(hp, wpos[pp], j);
  }
  for (int o = tid; o < CDIM * NPROP; o += 256) {
    int c = o / NPROP, pp = o - c * NPROP;
    out[(size_t)b * CDIM * NPROP + o] =
        feat[(size_t)wrow[pp] * CDIM + c] + Wc[c * NCLS + wcls[pp]] + bc[c];
  }
}

// ---------------------------------------------------------------------------
// ws layout (bytes):
//   [0)          dense_heat : B*10*HW*4 = 10,368,000
//   [10368000)   hist       : B*4096*4  =     32,768
//   [10400768)   rowmap     : B*HW*4    =  1,036,800
//   [11437568)   sel        : B*4096*8  =     65,536
//   [11503104)   cnts       : sel_cnt[2], selT[2]
//   [11503168)   val        : 800000*4  =  3,200,000
// total ~14.7 MB
// ---------------------------------------------------------------------------
extern "C" void kernel_launch(void* const* d_in, const int* in_sizes, int n_in,
                              void* d_out, int out_size, void* d_ws,
                              size_t ws_size, hipStream_t stream) {
  const float* feat = (const float*)d_in[0];
  const float* W1 = (const float*)d_in[1];
  const float* b1 = (const float*)d_in[2];
  const float* W2 = (const float*)d_in[3];
  const float* b2 = (const float*)d_in[4];
  const float* Wc = (const float*)d_in[5];
  const float* bc = (const float*)d_in[6];
  const int* idxs = (const int*)d_in[7];
  float* out = (float*)d_out;

  char* ws = (char*)d_ws;
  float* dense_heat = (float*)(ws + 0);
  unsigned int* hist = (unsigned int*)(ws + 10368000);
  int* rowmap = (int*)(ws + 10400768);
  unsigned long long* sel = (unsigned long long*)(ws + 11437568);
  int* cnts = (int*)(ws + 11503104);
  int* sel_cnt = cnts + 0;
  int* selT = cnts + 2;
  float* val = (float*)(ws + 11503168);

  hipMemsetAsync(dense_heat, 0, (size_t)NB * NCLS * HW * sizeof(float), stream);
  hipMemsetAsync(hist, 0, (size_t)NB * HBINS * sizeof(unsigned int), stream);
  hipMemsetAsync(cnts, 0, 4 * sizeof(int), stream);

  k_head<<<NROWS / RPB, 256, 0, stream>>>(feat, W1, b1, W2, b2, idxs, dense_heat,
                                          rowmap);
  k_hist<<<NRC / 256, 256, 0, stream>>>(dense_heat, idxs, val, hist);
  k_thresh<<<NB, 256, 0, stream>>>(hist, selT);
  k_collect<<<NRC / 256, 256, 0, stream>>>(val, idxs, selT, sel, sel_cnt);
  k_final<<<NB, 256, 0, stream>>>(sel, sel_cnt, dense_heat, rowmap, feat, Wc, bc,
                                  out);
}

// Round 6
// 233.711 us; speedup vs baseline: 2.0713x; 1.3489x over previous
//
#include <hip/hip_runtime.h>

#define HW 129600
#define WG 360
#define HG 360
#define NCLS 10
#define NPROP 200
#define CDIM 128
#define NROWS 80000
#define NB 2
#define NPB (NROWS / NB)    // rows are batch-sorted: row<40000 -> b=0
#define SEL_CAP 4096
#define HBINS 4096          // heat in (0,1]: (bits>>18) <= 4064
#define RPB 64              // rows per k_head block
#define NRC (NROWS * NCLS)  // 800,000 sparse NMS sites
#define SPB 1024            // sites per k_hist block

// ---------------------------------------------------------------------------
// Async global->LDS DMA, 16B per lane. LDS dest must be wave-uniform base;
// HW writes lane i at base + i*16 (guide §5 / m97, m104).
// ---------------------------------------------------------------------------
__device__ __forceinline__ void lds_cp16(float* l, const float* g) {
  __builtin_amdgcn_global_load_lds(
      (const __attribute__((address_space(1))) void*)g,
      (__attribute__((address_space(3))) void*)l, 16, 0, 0);
}

// ---------------------------------------------------------------------------
// Shared NMS value: 3x3 local-max suppression, classes 8/9 pass-through,
// border rows/cols suppressed (reference's local_max stays 0 there).
// ---------------------------------------------------------------------------
__device__ __forceinline__ float nms_val(const float* __restrict__ hp, int pos,
                                         int cl) {
  float v = hp[pos];
  if (cl >= 8) return v;
  int y = pos / WG, x = pos - y * WG;
  if (y == 0 || y == HG - 1 || x == 0 || x == WG - 1) return 0.f;
  float m = v;
  m = fmaxf(m, hp[pos - 1]);
  m = fmaxf(m, hp[pos + 1]);
  m = fmaxf(m, hp[pos - WG - 1]);
  m = fmaxf(m, hp[pos - WG]);
  m = fmaxf(m, hp[pos - WG + 1]);
  m = fmaxf(m, hp[pos + WG - 1]);
  m = fmaxf(m, hp[pos + WG]);
  m = fmaxf(m, hp[pos + WG + 1]);
  return (v == m) ? v : 0.f;
}

// ---------------------------------------------------------------------------
// K1: fused MLP head. 256 thr / 64 rows; LDS tiling (acc[8][4]) with
// DOUBLE-BUFFERED async global->LDS staging (no staging VGPRs — R5's
// register prefetch hit VGPR=220/occ 10%). FMA order identical to R2-R5.
// LDS 54.8 KB -> 2 blocks/CU.
// ---------------------------------------------------------------------------
__global__ __launch_bounds__(256) void k_head(
    const float* __restrict__ feat, const float* __restrict__ W1,
    const float* __restrict__ b1, const float* __restrict__ W2,
    const float* __restrict__ b2, const int* __restrict__ idxs,
    float* __restrict__ dense_heat, int* __restrict__ rowmap) {
  __shared__ __align__(16) float lds_w[2][32 * 128];   // 32KB: W1 chunks
  __shared__ __align__(16) float lds_f[2][RPB * 32];   // 16KB: f chunks
  __shared__ __align__(16) float lds_w2t[NCLS * 128];  // 5KB: W2^T
  __shared__ int lds_b[RPB];
  __shared__ int lds_p[RPB];
  const int tid = threadIdx.x;
  const int row0 = blockIdx.x * RPB;
  const int tc = tid & 31;
  const int tr = tid >> 5;
  const int wv = tid >> 6;     // wave id (uniform within wave)
  const int lane = tid & 63;

  // issue async stage of chunk kt into buffer nb (wave-uniform LDS bases)
  auto stage = [&](int kt, int nb) {
#pragma unroll
    for (int c = 0; c < 4; ++c) {
      const int off = (wv * 4 + c) * 256;  // wave-uniform float offset
      lds_cp16(&lds_w[nb][off], W1 + kt * 4096 + off + lane * 4);
    }
#pragma unroll
    for (int c = 0; c < 2; ++c) {
      const int off = (wv * 2 + c) * 256;
      const int fidx = off + lane * 4;
      const int r = fidx >> 5, kk = fidx & 31;
      lds_cp16(&lds_f[nb][off],
               feat + (size_t)(row0 + r) * CDIM + kt * 32 + kk);
    }
  };

  stage(0, 0);  // preload chunk 0 (drained by the syncthreads below)
  for (int i = tid; i < CDIM * NCLS; i += 256) {
    int k = i / NCLS, j = i - k * NCLS;
    lds_w2t[j * 128 + k] = W2[i];
  }
  if (tid < RPB) {
    int row = row0 + tid;
    int bb = idxs[row * 3 + 0];
    int yy = idxs[row * 3 + 1];
    int xx = idxs[row * 3 + 2];
    lds_b[tid] = bb;
    lds_p[tid] = yy * WG + xx;
    rowmap[(size_t)bb * HW + yy * WG + xx] = row;
  }
  __syncthreads();

  float acc[8][4];
#pragma unroll
  for (int r = 0; r < 8; ++r)
#pragma unroll
    for (int c = 0; c < 4; ++c) acc[r][c] = 0.f;

  for (int kt = 0; kt < 4; ++kt) {
    const int cb = kt & 1;
    if (kt < 3) stage(kt + 1, cb ^ 1);  // async; lands during compute below
#pragma unroll
    for (int kg = 0; kg < 8; ++kg) {
      float4 w0 = *(const float4*)(&lds_w[cb][(kg * 4 + 0) * 128 + tc * 4]);
      float4 w1 = *(const float4*)(&lds_w[cb][(kg * 4 + 1) * 128 + tc * 4]);
      float4 w2 = *(const float4*)(&lds_w[cb][(kg * 4 + 2) * 128 + tc * 4]);
      float4 w3 = *(const float4*)(&lds_w[cb][(kg * 4 + 3) * 128 + tc * 4]);
#pragma unroll
      for (int r = 0; r < 8; ++r) {
        float4 fv = *(const float4*)(&lds_f[cb][(tr * 8 + r) * 32 + kg * 4]);
        acc[r][0] = fmaf(fv.x, w0.x, acc[r][0]);
        acc[r][0] = fmaf(fv.y, w1.x, acc[r][0]);
        acc[r][0] = fmaf(fv.z, w2.x, acc[r][0]);
        acc[r][0] = fmaf(fv.w, w3.x, acc[r][0]);
        acc[r][1] = fmaf(fv.x, w0.y, acc[r][1]);
        acc[r][1] = fmaf(fv.y, w1.y, acc[r][1]);
        acc[r][1] = fmaf(fv.z, w2.y, acc[r][1]);
        acc[r][1] = fmaf(fv.w, w3.y, acc[r][1]);
        acc[r][2] = fmaf(fv.x, w0.z, acc[r][2]);
        acc[r][2] = fmaf(fv.y, w1.z, acc[r][2]);
        acc[r][2] = fmaf(fv.z, w2.z, acc[r][2]);
        acc[r][2] = fmaf(fv.w, w3.z, acc[r][2]);
        acc[r][3] = fmaf(fv.x, w0.w, acc[r][3]);
        acc[r][3] = fmaf(fv.y, w1.w, acc[r][3]);
        acc[r][3] = fmaf(fv.z, w2.w, acc[r][3]);
        acc[r][3] = fmaf(fv.w, w3.w, acc[r][3]);
      }
    }
    __syncthreads();  // drains prefetch (vmcnt) + protects buffer swap
  }

  // ---- layer 2, two 32-row halves through lds_w[0] (16KB) ----
  float* hbuf = &lds_w[0][0];
  float4 b1v = *(const float4*)(b1 + tc * 4);
#pragma unroll
  for (int half = 0; half < 2; ++half) {
    if ((tr >> 2) == half) {  // wave-uniform: waves 0,1 = half0; 2,3 = half1
      int ltr = tr & 3;
#pragma unroll
      for (int r = 0; r < 8; ++r) {
        float4 h;
        h.x = fmaxf(acc[r][0] + b1v.x, 0.f);
        h.y = fmaxf(acc[r][1] + b1v.y, 0.f);
        h.z = fmaxf(acc[r][2] + b1v.z, 0.f);
        h.w = fmaxf(acc[r][3] + b1v.w, 0.f);
        *(float4*)(hbuf + (ltr * 8 + r) * 128 + tc * 4) = h;
      }
    }
    __syncthreads();
    for (int o = tid; o < 32 * NCLS; o += 256) {
      int r = o / NCLS, j = o - r * NCLS;
      float s = b2[j];
      for (int i4 = 0; i4 < 32; ++i4) {
        int k4 = (i4 + tid) & 31;
        float4 hv = *(const float4*)(hbuf + r * 128 + k4 * 4);
        float4 wv2 = *(const float4*)(&lds_w2t[j * 128 + k4 * 4]);
        s = fmaf(hv.x, wv2.x, s);
        s = fmaf(hv.y, wv2.y, s);
        s = fmaf(hv.z, wv2.z, s);
        s = fmaf(hv.w, wv2.w, s);
      }
      float heat = 1.0f / (1.0f + expf(-s));
      int gr = half * 32 + r;
      dense_heat[((size_t)lds_b[gr] * NCLS + j) * HW + lds_p[gr]] = heat;
    }
    __syncthreads();
  }
}

// ---------------------------------------------------------------------------
// K2: SPARSE NMS + histogram over the 800k occupied sites. 1024 sites/block
// (4/thread) amortizes the 4096-bin LDS hist init/flush 8x vs R5. Batch from
// row index (rows are batch-sorted). Stores NMS value to val[] for collect.
// ---------------------------------------------------------------------------
__global__ __launch_bounds__(256) void k_hist(
    const float* __restrict__ dense_heat, const int* __restrict__ idxs,
    float* __restrict__ val, unsigned int* __restrict__ hist) {
  __shared__ unsigned int lh[HBINS];
  const int tid = threadIdx.x;
  const int base = blockIdx.x * SPB;
  const int blk_b = ((base / NCLS) >= NPB) ? 1 : 0;
  for (int i = tid; i < HBINS; i += 256) lh[i] = 0;
  __syncthreads();
#pragma unroll
  for (int s = 0; s < SPB; s += 256) {
    const int t = base + s + tid;
    if (t < NRC) {
      const int row = t / NCLS;
      const int cl = t - row * NCLS;
      const int bb = (row >= NPB) ? 1 : 0;
      const int pos = idxs[row * 3 + 1] * WG + idxs[row * 3 + 2];
      float v = nms_val(dense_heat + ((size_t)bb * NCLS + cl) * HW, pos, cl);
      val[t] = v;
      if (v > 0.f) {
        unsigned int bin = __float_as_uint(v) >> 18;
        if (bb == blk_b)
          atomicAdd(&lh[bin], 1u);
        else  // only the single batch-straddling block takes this path
          atomicAdd(&hist[(size_t)bb * HBINS + bin], 1u);
      }
    }
  }
  __syncthreads();
  unsigned int* gh = hist + (size_t)blk_b * HBINS;
  for (int i = tid; i < HBINS; i += 256) {
    unsigned int c = lh[i];
    if (c) atomicAdd(&gh[i], c);
  }
}

// ---------------------------------------------------------------------------
// K3: threshold bin T per batch: count(bin > T) < 200 <= count(bin >= T).
// ---------------------------------------------------------------------------
__global__ __launch_bounds__(256) void k_thresh(
    const unsigned int* __restrict__ hist, int* __restrict__ selT) {
  __shared__ unsigned int coarse[256];
  const int b = blockIdx.x;
  const unsigned int* h = hist + (size_t)b * HBINS;
  unsigned int s = 0;
#pragma unroll
  for (int i = 0; i < HBINS / 256; ++i) s += h[threadIdx.x * (HBINS / 256) + i];
  coarse[threadIdx.x] = s;
  __syncthreads();
  if (threadIdx.x == 0) {
    unsigned int cum = 0;
    int T = 0;
    int ci = 255;
    for (; ci >= 0; --ci) {
      if (cum + coarse[ci] >= NPROP) break;
      cum += coarse[ci];
    }
    if (ci >= 0) {
      int t = 15;
      for (; t > 0; --t) {
        unsigned int c = h[ci * 16 + t];
        if (cum + c >= NPROP) break;
        cum += c;
      }
      T = ci * 16 + t;
    }
    selT[b] = T;
  }
}

// ---------------------------------------------------------------------------
// K4: compact survivors from stored vals (coalesced; no re-stencil).
// Per-batch ballots + shfl-from-leader handle the batch-straddling wave.
// ---------------------------------------------------------------------------
__global__ __launch_bounds__(256) void k_collect(
    const float* __restrict__ val, const int* __restrict__ idxs,
    const int* __restrict__ selT, unsigned long long* __restrict__ sel,
    int* __restrict__ sel_cnt) {
  const int t = blockIdx.x * 256 + threadIdx.x;  // exact grid
  const int row = t / NCLS;
  const int cl = t - row * NCLS;
  const int bb = (row >= NPB) ? 1 : 0;
  float v = val[t];
  unsigned int bits = __float_as_uint(v);
  bool pred = (v > 0.f) && ((int)(bits >> 18) >= selT[bb]);
  unsigned long long m0 = __ballot(pred && (bb == 0));
  unsigned long long m1 = __ballot(pred && (bb == 1));
  if (pred) {
    unsigned long long mask = bb ? m1 : m0;
    int lane = threadIdx.x & 63;
    int leader = __ffsll((unsigned long long)mask) - 1;
    int lb = __popcll(mask & ((1ull << lane) - 1ull));
    int base = 0;
    if (lane == leader) base = atomicAdd(&sel_cnt[bb], (int)__popcll(mask));
    base = __shfl(base, leader, 64);
    unsigned int pos =
        (unsigned int)(idxs[row * 3 + 1] * WG + idxs[row * 3 + 2]);
    unsigned int gidx = (unsigned int)cl * HW + pos;
    // key: heat bits desc, then smaller gidx first (jax top_k tie-break)
    unsigned long long key =
        ((unsigned long long)bits << 32) | (unsigned long long)(~gidx);
    int slot = base + lb;
    if (slot < SEL_CAP) sel[(size_t)bb * SEL_CAP + slot] = key;
  }
}

// ---------------------------------------------------------------------------
// K5: exact top-200 by rank-counting (keys unique), cooperative emit.
// ---------------------------------------------------------------------------
__global__ __launch_bounds__(256) void k_final(
    const unsigned long long* __restrict__ sel, const int* __restrict__ sel_cnt,
    const float* __restrict__ dense_heat, const int* __restrict__ rowmap,
    const float* __restrict__ feat, const float* __restrict__ Wc,
    const float* __restrict__ bc, float* __restrict__ out) {
  __shared__ unsigned long long sk[SEL_CAP];
  __shared__ unsigned long long winners[NPROP];
  __shared__ int wpos[NPROP];
  __shared__ int wcls[NPROP];
  __shared__ int wrow[NPROP];
  const int b = blockIdx.x;
  const int tid = threadIdx.x;
  int M = sel_cnt[b];
  if (M > SEL_CAP) M = SEL_CAP;
  for (int i = tid; i < M; i += 256) sk[i] = sel[(size_t)b * SEL_CAP + i];
  __syncthreads();
  for (int i = tid; i < M; i += 256) {
    unsigned long long key = sk[i];
    int rank = 0;
    for (int j = 0; j < M; ++j) rank += (sk[j] > key) ? 1 : 0;
    if (rank < NPROP) winners[rank] = key;
  }
  __syncthreads();
  if (tid < NPROP) {
    unsigned long long key = winners[tid];
    unsigned int gidx = ~((unsigned int)(key & 0xFFFFFFFFull));
    int cls = (int)(gidx / HW);
    int pos = (int)(gidx - (unsigned int)cls * HW);
    int y = pos / WG, x = pos - y * WG;
    wpos[tid] = pos;
    wcls[tid] = cls;
    wrow[tid] = rowmap[(size_t)b * HW + pos];
    out[51200 + ((size_t)b * NPROP + tid) * 2 + 0] = (float)x;
    out[51200 + ((size_t)b * NPROP + tid) * 2 + 1] = (float)y;
    out[56000 + b * NPROP + tid] = (float)cls;
  }
  __syncthreads();
  for (int o = tid; o < NCLS * NPROP; o += 256) {
    int j = o / NPROP, pp = o - j * NPROP;
    const float* hp = dense_heat + ((size_t)b * NCLS + j) * HW;
    out[52000 + (size_t)b * NCLS * NPROP + o] = nms_val(hp, wpos[pp], j);
  }
  for (int o = tid; o < CDIM * NPROP; o += 256) {
    int c = o / NPROP, pp = o - c * NPROP;
    out[(size_t)b * CDIM * NPROP + o] =
        feat[(size_t)wrow[pp] * CDIM + c] + Wc[c * NCLS + wcls[pp]] + bc[c];
  }
}

// ---------------------------------------------------------------------------
// ws layout (bytes):
//   [0)          dense_heat : B*10*HW*4 = 10,368,000
//   [10368000)   hist       : B*4096*4  =     32,768
//   [10400768)   rowmap     : B*HW*4    =  1,036,800
//   [11437568)   sel        : B*4096*8  =     65,536
//   [11503104)   cnts       : sel_cnt[2], selT[2]
//   [11503168)   val        : 800000*4  =  3,200,000
// total ~14.7 MB
// ---------------------------------------------------------------------------
extern "C" void kernel_launch(void* const* d_in, const int* in_sizes, int n_in,
                              void* d_out, int out_size, void* d_ws,
                              size_t ws_size, hipStream_t stream) {
  const float* feat = (const float*)d_in[0];
  const float* W1 = (const float*)d_in[1];
  const float* b1 = (const float*)d_in[2];
  const float* W2 = (const float*)d_in[3];
  const float* b2 = (const float*)d_in[4];
  const float* Wc = (const float*)d_in[5];
  const float* bc = (const float*)d_in[6];
  const int* idxs = (const int*)d_in[7];
  float* out = (float*)d_out;

  char* ws = (char*)d_ws;
  float* dense_heat = (float*)(ws + 0);
  unsigned int* hist = (unsigned int*)(ws + 10368000);
  int* rowmap = (int*)(ws + 10400768);
  unsigned long long* sel = (unsigned long long*)(ws + 11437568);
  int* cnts = (int*)(ws + 11503104);
  int* sel_cnt = cnts + 0;
  int* selT = cnts + 2;
  float* val = (float*)(ws + 11503168);

  hipMemsetAsync(dense_heat, 0, (size_t)NB * NCLS * HW * sizeof(float), stream);
  hipMemsetAsync(hist, 0, (size_t)NB * HBINS * sizeof(unsigned int), stream);
  hipMemsetAsync(cnts, 0, 4 * sizeof(int), stream);

  k_head<<<NROWS / RPB, 256, 0, stream>>>(feat, W1, b1, W2, b2, idxs, dense_heat,
                                          rowmap);
  k_hist<<<(NRC + SPB - 1) / SPB, 256, 0, stream>>>(dense_heat, idxs, val, hist);
  k_thresh<<<NB, 256, 0, stream>>>(hist, selT);
  k_collect<<<NRC / 256, 256, 0, stream>>>(val, idxs, selT, sel, sel_cnt);
  k_final<<<NB, 256, 0, stream>>>(sel, sel_cnt, dense_heat, rowmap, feat, Wc, bc,
                                  out);
}

// Round 7
// 202.655 us; speedup vs baseline: 2.3887x; 1.1532x over previous
//
#include <hip/hip_runtime.h>

#define HW 129600
#define WG 360
#define HG 360
#define NCLS 10
#define NPROP 200
#define CDIM 128
#define NROWS 80000
#define NB 2
#define NPB (NROWS / NB)    // rows are batch-sorted: row<40000 -> b=0
#define SEL_CAP 4096
#define HBINS 4096          // heat in (0,1]: (bits>>18) <= 4064
#define RPB 64              // rows per k_head block
#define PSTR 12             // pixel stride (floats): 10 classes + 2 pad, 48B

// ---------------------------------------------------------------------------
// Async global->LDS DMA, 16B per lane; LDS dest wave-uniform base (m97/m104).
// ---------------------------------------------------------------------------
__device__ __forceinline__ void lds_cp16(float* l, const float* g) {
  __builtin_amdgcn_global_load_lds(
      (const __attribute__((address_space(1))) void*)g,
      (__attribute__((address_space(3))) void*)l, 16, 0, 0);
}

__device__ __forceinline__ float4 fmax4(float4 a, float4 b) {
  float4 r;
  r.x = fmaxf(a.x, b.x);
  r.y = fmaxf(a.y, b.y);
  r.z = fmaxf(a.z, b.z);
  r.w = fmaxf(a.w, b.w);
  return r;
}

// ---------------------------------------------------------------------------
// K1: fused MLP head. 256 thr / 64 rows; LDS tiling (acc[8][4]) with
// double-buffered async global->LDS staging. FMA order identical to R2-R6
// (bit-exact heat). W2^T staged into freed lds_f after the main loop:
// LDS 48.5 KB -> 3 blocks/CU (was 2).
// Heat written PIXEL-MAJOR: dense[(b*HW+pos)*12 + cls].
// ---------------------------------------------------------------------------
__global__ __launch_bounds__(256) void k_head(
    const float* __restrict__ feat, const float* __restrict__ W1,
    const float* __restrict__ b1, const float* __restrict__ W2,
    const float* __restrict__ b2, const int* __restrict__ idxs,
    float* __restrict__ dense_heat, int* __restrict__ rowmap) {
  __shared__ __align__(16) float lds_w[2][32 * 128];  // 32KB: W1 chunks
  __shared__ __align__(16) float lds_f[2][RPB * 32];  // 16KB: f chunks; W2^T later
  __shared__ int lds_b[RPB];
  __shared__ int lds_p[RPB];
  const int tid = threadIdx.x;
  const int row0 = blockIdx.x * RPB;
  const int tc = tid & 31;
  const int tr = tid >> 5;
  const int wv = tid >> 6;  // wave id (uniform within wave)
  const int lane = tid & 63;

  auto stage = [&](int kt, int nb) {
#pragma unroll
    for (int c = 0; c < 4; ++c) {
      const int off = (wv * 4 + c) * 256;  // wave-uniform float offset
      lds_cp16(&lds_w[nb][off], W1 + kt * 4096 + off + lane * 4);
    }
#pragma unroll
    for (int c = 0; c < 2; ++c) {
      const int off = (wv * 2 + c) * 256;
      const int fidx = off + lane * 4;
      const int r = fidx >> 5, kk = fidx & 31;
      lds_cp16(&lds_f[nb][off],
               feat + (size_t)(row0 + r) * CDIM + kt * 32 + kk);
    }
  };

  stage(0, 0);
  if (tid < RPB) {
    int row = row0 + tid;
    int bb = idxs[row * 3 + 0];
    int yy = idxs[row * 3 + 1];
    int xx = idxs[row * 3 + 2];
    lds_b[tid] = bb;
    lds_p[tid] = yy * WG + xx;
    rowmap[(size_t)bb * HW + yy * WG + xx] = row;
  }
  __syncthreads();

  float acc[8][4];
#pragma unroll
  for (int r = 0; r < 8; ++r)
#pragma unroll
    for (int c = 0; c < 4; ++c) acc[r][c] = 0.f;

  for (int kt = 0; kt < 4; ++kt) {
    const int cb = kt & 1;
    if (kt < 3) stage(kt + 1, cb ^ 1);  // async; lands during compute
#pragma unroll
    for (int kg = 0; kg < 8; ++kg) {
      float4 w0 = *(const float4*)(&lds_w[cb][(kg * 4 + 0) * 128 + tc * 4]);
      float4 w1 = *(const float4*)(&lds_w[cb][(kg * 4 + 1) * 128 + tc * 4]);
      float4 w2 = *(const float4*)(&lds_w[cb][(kg * 4 + 2) * 128 + tc * 4]);
      float4 w3 = *(const float4*)(&lds_w[cb][(kg * 4 + 3) * 128 + tc * 4]);
#pragma unroll
      for (int r = 0; r < 8; ++r) {
        float4 fv = *(const float4*)(&lds_f[cb][(tr * 8 + r) * 32 + kg * 4]);
        acc[r][0] = fmaf(fv.x, w0.x, acc[r][0]);
        acc[r][0] = fmaf(fv.y, w1.x, acc[r][0]);
        acc[r][0] = fmaf(fv.z, w2.x, acc[r][0]);
        acc[r][0] = fmaf(fv.w, w3.x, acc[r][0]);
        acc[r][1] = fmaf(fv.x, w0.y, acc[r][1]);
        acc[r][1] = fmaf(fv.y, w1.y, acc[r][1]);
        acc[r][1] = fmaf(fv.z, w2.y, acc[r][1]);
        acc[r][1] = fmaf(fv.w, w3.y, acc[r][1]);
        acc[r][2] = fmaf(fv.x, w0.z, acc[r][2]);
        acc[r][2] = fmaf(fv.y, w1.z, acc[r][2]);
        acc[r][2] = fmaf(fv.z, w2.z, acc[r][2]);
        acc[r][2] = fmaf(fv.w, w3.z, acc[r][2]);
        acc[r][3] = fmaf(fv.x, w0.w, acc[r][3]);
        acc[r][3] = fmaf(fv.y, w1.w, acc[r][3]);
        acc[r][3] = fmaf(fv.z, w2.w, acc[r][3]);
        acc[r][3] = fmaf(fv.w, w3.w, acc[r][3]);
      }
    }
    __syncthreads();  // drains prefetch + protects buffer swap
  }

  // stage W2^T into freed lds_f (main loop done reading it)
  float* w2t = &lds_f[0][0];  // 1280 floats
  for (int i = tid; i < CDIM * NCLS; i += 256) {
    int k = i / NCLS, j = i - k * NCLS;
    w2t[j * 128 + k] = W2[i];
  }
  __syncthreads();

  // ---- layer 2, two 32-row halves through lds_w[0] (16KB) ----
  float* hbuf = &lds_w[0][0];
  float4 b1v = *(const float4*)(b1 + tc * 4);
#pragma unroll
  for (int half = 0; half < 2; ++half) {
    if ((tr >> 2) == half) {  // wave-uniform: waves 0,1 = half0; 2,3 = half1
      int ltr = tr & 3;
#pragma unroll
      for (int r = 0; r < 8; ++r) {
        float4 h;
        h.x = fmaxf(acc[r][0] + b1v.x, 0.f);
        h.y = fmaxf(acc[r][1] + b1v.y, 0.f);
        h.z = fmaxf(acc[r][2] + b1v.z, 0.f);
        h.w = fmaxf(acc[r][3] + b1v.w, 0.f);
        *(float4*)(hbuf + (ltr * 8 + r) * 128 + tc * 4) = h;
      }
    }
    __syncthreads();
    for (int o = tid; o < 32 * NCLS; o += 256) {
      int r = o / NCLS, j = o - r * NCLS;
      float s = b2[j];
      for (int i4 = 0; i4 < 32; ++i4) {
        int k4 = (i4 + tid) & 31;
        float4 hv = *(const float4*)(hbuf + r * 128 + k4 * 4);
        float4 wv2 = *(const float4*)(w2t + j * 128 + k4 * 4);
        s = fmaf(hv.x, wv2.x, s);
        s = fmaf(hv.y, wv2.y, s);
        s = fmaf(hv.z, wv2.z, s);
        s = fmaf(hv.w, wv2.w, s);
      }
      float heat = 1.0f / (1.0f + expf(-s));
      int gr = half * 32 + r;
      dense_heat[((size_t)lds_b[gr] * HW + lds_p[gr]) * PSTR + j] = heat;
    }
    __syncthreads();
  }
}

// ---------------------------------------------------------------------------
// K2: sparse NMS + histogram, ONE THREAD PER ROW on pixel-major heat.
// Per row: 9 pixels x (2 float4 + ...) vector loads, all 10 classes at once.
// Stores suppressed values to val[row*12..] (coalesced 48B/thread).
// ---------------------------------------------------------------------------
__global__ __launch_bounds__(256) void k_hist(
    const float* __restrict__ dense_heat, const int* __restrict__ idxs,
    float* __restrict__ val, unsigned int* __restrict__ hist) {
  __shared__ unsigned int lh[HBINS];
  const int tid = threadIdx.x;
  const int row = blockIdx.x * 256 + tid;
  const int blk_b = (blockIdx.x * 256 >= NPB) ? 1 : 0;
  for (int i = tid; i < HBINS; i += 256) lh[i] = 0;
  __syncthreads();

  float v[10];
  int bb = 0;
  const bool valid = row < NROWS;
  if (valid) {
    bb = (row >= NPB) ? 1 : 0;
    const int y = idxs[row * 3 + 1];
    const int x = idxs[row * 3 + 2];
    const int pos = y * WG + x;
    const float* base = dense_heat + ((size_t)bb * HW + pos) * PSTR;
    const bool interior = (y > 0 && y < HG - 1 && x > 0 && x < WG - 1);
    // neighbor pixel offsets (in PSTR units)
    const int d[8] = {-1, 1, -WG - 1, -WG, -WG + 1, WG - 1, WG, WG + 1};
#pragma unroll
    for (int g = 0; g < 2; ++g) {
      float4 cen = *(const float4*)(base + g * 4);
      if (interior) {
        float4 m = cen;
#pragma unroll
        for (int n = 0; n < 8; ++n)
          m = fmax4(m, *(const float4*)(base + d[n] * PSTR + g * 4));
        v[g * 4 + 0] = (cen.x == m.x) ? cen.x : 0.f;
        v[g * 4 + 1] = (cen.y == m.y) ? cen.y : 0.f;
        v[g * 4 + 2] = (cen.z == m.z) ? cen.z : 0.f;
        v[g * 4 + 3] = (cen.w == m.w) ? cen.w : 0.f;
      } else {
        v[g * 4 + 0] = v[g * 4 + 1] = v[g * 4 + 2] = v[g * 4 + 3] = 0.f;
      }
    }
    float2 c89 = *(const float2*)(base + 8);
    v[8] = c89.x;
    v[9] = c89.y;
    // store suppressed vals (stride 12, 16B-aligned)
    float4 s0 = {v[0], v[1], v[2], v[3]};
    float4 s1 = {v[4], v[5], v[6], v[7]};
    float4 s2 = {v[8], v[9], 0.f, 0.f};
    *(float4*)(val + (size_t)row * PSTR + 0) = s0;
    *(float4*)(val + (size_t)row * PSTR + 4) = s1;
    *(float4*)(val + (size_t)row * PSTR + 8) = s2;
#pragma unroll
    for (int c = 0; c < 10; ++c) {
      if (v[c] > 0.f) {
        unsigned int bin = __float_as_uint(v[c]) >> 18;
        if (bb == blk_b)
          atomicAdd(&lh[bin], 1u);
        else  // only the batch-straddling block takes this path
          atomicAdd(&hist[(size_t)bb * HBINS + bin], 1u);
      }
    }
  }
  __syncthreads();
  unsigned int* gh = hist + (size_t)blk_b * HBINS;
  for (int i = tid; i < HBINS; i += 256) {
    unsigned int c = lh[i];
    if (c) atomicAdd(&gh[i], c);
  }
}

// ---------------------------------------------------------------------------
// K3: inline per-block threshold (L2-hot 16KB hist) + compaction from val.
// One thread per row, 10 classes; per-class/per-batch ballots.
// ---------------------------------------------------------------------------
__global__ __launch_bounds__(256) void k_collect(
    const float* __restrict__ val, const int* __restrict__ idxs,
    const unsigned int* __restrict__ hist, unsigned long long* __restrict__ sel,
    int* __restrict__ sel_cnt) {
  __shared__ unsigned int coarse[256];
  __shared__ int sT[2];
  const int tid = threadIdx.x;
  for (int bb = 0; bb < NB; ++bb) {
    const unsigned int* h = hist + (size_t)bb * HBINS;
    unsigned int s = 0;
#pragma unroll
    for (int i = 0; i < HBINS / 256; ++i) s += h[tid * (HBINS / 256) + i];
    coarse[tid] = s;
    __syncthreads();
    if (tid == 0) {
      unsigned int cum = 0;
      int T = 0;
      int ci = 255;
      for (; ci >= 0; --ci) {
        if (cum + coarse[ci] >= NPROP) break;
        cum += coarse[ci];
      }
      if (ci >= 0) {
        int t = 15;
        for (; t > 0; --t) {
          unsigned int c = h[ci * 16 + t];
          if (cum + c >= NPROP) break;
          cum += c;
        }
        T = ci * 16 + t;
      }
      sT[bb] = T;
    }
    __syncthreads();
  }
  const int row = blockIdx.x * 256 + tid;
  const bool valid = row < NROWS;
  const int bb = (valid && row >= NPB) ? 1 : 0;
  const int T = sT[bb];
  float v[12];
  int pos = 0;
  if (valid) {
    *(float4*)(v + 0) = *(const float4*)(val + (size_t)row * PSTR + 0);
    *(float4*)(v + 4) = *(const float4*)(val + (size_t)row * PSTR + 4);
    *(float4*)(v + 8) = *(const float4*)(val + (size_t)row * PSTR + 8);
    pos = idxs[row * 3 + 1] * WG + idxs[row * 3 + 2];
  }
  const int lane = tid & 63;
#pragma unroll
  for (int cl = 0; cl < 10; ++cl) {
    float vv = valid ? v[cl] : 0.f;
    unsigned int bits = __float_as_uint(vv);
    bool pred = (vv > 0.f) && ((int)(bits >> 18) >= T);
    unsigned long long m0 = __ballot(pred && (bb == 0));
    unsigned long long m1 = __ballot(pred && (bb == 1));
    if (pred) {
      unsigned long long mask = bb ? m1 : m0;
      int leader = __ffsll((unsigned long long)mask) - 1;
      int lb = __popcll(mask & ((1ull << lane) - 1ull));
      int base = 0;
      if (lane == leader) base = atomicAdd(&sel_cnt[bb], (int)__popcll(mask));
      base = __shfl(base, leader, 64);
      unsigned int gidx = (unsigned int)cl * HW + (unsigned int)pos;
      // key: heat bits desc, then smaller gidx first (jax top_k tie-break)
      unsigned long long key =
          ((unsigned long long)bits << 32) | (unsigned long long)(~gidx);
      int slot = base + lb;
      if (slot < SEL_CAP) sel[(size_t)bb * SEL_CAP + slot] = key;
    }
  }
}

// ---------------------------------------------------------------------------
// K4: exact top-200 by rank-counting (keys unique), cooperative emit.
// qhs comes straight from val[] (no re-stencil).
// ---------------------------------------------------------------------------
__global__ __launch_bounds__(256) void k_final(
    const unsigned long long* __restrict__ sel, const int* __restrict__ sel_cnt,
    const float* __restrict__ val, const int* __restrict__ rowmap,
    const float* __restrict__ feat, const float* __restrict__ Wc,
    const float* __restrict__ bc, float* __restrict__ out) {
  __shared__ unsigned long long sk[SEL_CAP];
  __shared__ unsigned long long winners[NPROP];
  __shared__ int wcls[NPROP];
  __shared__ int wrow[NPROP];
  const int b = blockIdx.x;
  const int tid = threadIdx.x;
  int M = sel_cnt[b];
  if (M > SEL_CAP) M = SEL_CAP;
  for (int i = tid; i < M; i += 256) sk[i] = sel[(size_t)b * SEL_CAP + i];
  __syncthreads();
  for (int i = tid; i < M; i += 256) {
    unsigned long long key = sk[i];
    int rank = 0;
    for (int j = 0; j < M; ++j) rank += (sk[j] > key) ? 1 : 0;
    if (rank < NPROP) winners[rank] = key;
  }
  __syncthreads();
  if (tid < NPROP) {
    unsigned long long key = winners[tid];
    unsigned int gidx = ~((unsigned int)(key & 0xFFFFFFFFull));
    int cls = (int)(gidx / HW);
    int pos = (int)(gidx - (unsigned int)cls * HW);
    int y = pos / WG, x = pos - y * WG;
    wcls[tid] = cls;
    wrow[tid] = rowmap[(size_t)b * HW + pos];
    out[51200 + ((size_t)b * NPROP + tid) * 2 + 0] = (float)x;
    out[51200 + ((size_t)b * NPROP + tid) * 2 + 1] = (float)y;
    out[56000 + b * NPROP + tid] = (float)cls;
  }
  __syncthreads();
  // qhs (B, NCLS, NPROP) at 52000 — direct gather from val
  for (int o = tid; o < NCLS * NPROP; o += 256) {
    int j = o / NPROP, pp = o - j * NPROP;
    out[52000 + (size_t)b * NCLS * NPROP + o] = val[(size_t)wrow[pp] * PSTR + j];
  }
  // qf (B, C, NPROP) at 0
  for (int o = tid; o < CDIM * NPROP; o += 256) {
    int c = o / NPROP, pp = o - c * NPROP;
    out[(size_t)b * CDIM * NPROP + o] =
        feat[(size_t)wrow[pp] * CDIM + c] + Wc[c * NCLS + wcls[pp]] + bc[c];
  }
}

// ---------------------------------------------------------------------------
// ws layout (bytes):
//   [0)          dense_heat : B*HW*12*4 = 12,441,600  (pixel-major)
//   [12441600)   hist       : B*4096*4  =     32,768
//   [12474368)   rowmap     : B*HW*4    =  1,036,800
//   [13511168)   sel        : B*4096*8  =     65,536
//   [13576704)   cnts       : sel_cnt[2] (16B, keeps val 16B-aligned)
//   [13576720)   val        : 80000*12*4 = 3,840,000
// total ~17.4 MB
// ---------------------------------------------------------------------------
extern "C" void kernel_launch(void* const* d_in, const int* in_sizes, int n_in,
                              void* d_out, int out_size, void* d_ws,
                              size_t ws_size, hipStream_t stream) {
  const float* feat = (const float*)d_in[0];
  const float* W1 = (const float*)d_in[1];
  const float* b1 = (const float*)d_in[2];
  const float* W2 = (const float*)d_in[3];
  const float* b2 = (const float*)d_in[4];
  const float* Wc = (const float*)d_in[5];
  const float* bc = (const float*)d_in[6];
  const int* idxs = (const int*)d_in[7];
  float* out = (float*)d_out;

  char* ws = (char*)d_ws;
  float* dense_heat = (float*)(ws + 0);
  unsigned int* hist = (unsigned int*)(ws + 12441600);
  int* rowmap = (int*)(ws + 12474368);
  unsigned long long* sel = (unsigned long long*)(ws + 13511168);
  int* sel_cnt = (int*)(ws + 13576704);
  float* val = (float*)(ws + 13576720);

  hipMemsetAsync(dense_heat, 0, (size_t)NB * HW * PSTR * sizeof(float), stream);
  hipMemsetAsync(hist, 0, (size_t)NB * HBINS * sizeof(unsigned int), stream);
  hipMemsetAsync(sel_cnt, 0, 2 * sizeof(int), stream);

  k_head<<<NROWS / RPB, 256, 0, stream>>>(feat, W1, b1, W2, b2, idxs, dense_heat,
                                          rowmap);
  k_hist<<<(NROWS + 255) / 256, 256, 0, stream>>>(dense_heat, idxs, val, hist);
  k_collect<<<(NROWS + 255) / 256, 256, 0, stream>>>(val, idxs, hist, sel,
                                                     sel_cnt);
  k_final<<<NB, 256, 0, stream>>>(sel, sel_cnt, val, rowmap, feat, Wc, bc, out);
}